// Round 3
// baseline (85.986 us; speedup 1.0000x reference)
//
#include <hip/hip_runtime.h>
#include <hip/hip_bf16.h>

#define NB 4096
#define NT 128                    // 4096 / 32 row-blocks
#define NTILES (NT * (NT + 1) / 2)   // 8256 upper-triangular 32x32 tiles

typedef short v8s __attribute__((ext_vector_type(8)));
typedef float v4f __attribute__((ext_vector_type(4)));

// ws layout: sq[4096] f32 (16 KB) | xb[4096*128] bf16 (1 MB) | Q[128][128][32] float2 (4 MB)
// Q[bi][b][r]: (num,den) partial for row r of 32-row block bi, from column-block b.
//   b >= bi: written by tile (bi,b)'s row partials.
//   b <  bi: written by tile (b,bi)'s column partials (symmetry of e and mask).
// Every slot written exactly once per iteration -> no atomics, no init, poison-safe.

__global__ __launch_bounds__(256) void prep_kernel(const float* __restrict__ x,
        float* __restrict__ sq, float* __restrict__ out,
        unsigned short* __restrict__ xb) {
    int tid = threadIdx.x;
    int row = blockIdx.x * 8 + (tid >> 5);   // 32 threads per row
    int lane = tid & 31;
    const float4* xg = (const float4*)x;
    float4 v = xg[row * 32 + lane];
    __hip_bfloat16 h0 = __float2bfloat16(v.x), h1 = __float2bfloat16(v.y);
    __hip_bfloat16 h2 = __float2bfloat16(v.z), h3 = __float2bfloat16(v.w);
    ushort4 u4;
    u4.x = *(unsigned short*)&h0; u4.y = *(unsigned short*)&h1;
    u4.z = *(unsigned short*)&h2; u4.w = *(unsigned short*)&h3;
    ((ushort4*)xb)[row * 32 + lane] = u4;
    float s = v.x * v.x + v.y * v.y + v.z * v.z + v.w * v.w;
    #pragma unroll
    for (int off = 16; off > 0; off >>= 1) s += __shfl_down(s, off);
    if (lane == 0) sq[row] = s;
    if (blockIdx.x == 0 && tid == 0) out[0] = 0.f;
}

// One WAVE per 32x32 upper-triangular tile. 8256 waves = 2064 blocks exactly.
// No LDS, no barriers: MFMA fragments load direct from L2-resident xb; row/col
// partial reductions in-register via shfl_xor; unique-slot stores to Q.
__global__ __launch_bounds__(256) void snn_wave(const unsigned short* __restrict__ xb,
        const int* __restrict__ y, const float* __restrict__ sqg,
        float2* __restrict__ Q) {
    const int tid = threadIdx.x;
    const int wid = tid >> 6;
    const int lane = tid & 63;
    const int lr = lane & 15;      // col within fragment
    const int q = lane >> 4;       // row-quad selector

    int t = blockIdx.x * 4 + wid;              // tile id, < 8256 always

    // decode t -> (bi, bj), bj >= bi.  start(bi) = 128*bi - bi*(bi-1)/2
    float sf = sqrtf((float)(66049 - 8 * t)); // (2*128+1)^2 = 66049
    int bi = (int)((257.0f - sf) * 0.5f);
    int st = 128 * bi - ((bi * (bi - 1)) >> 1);
    while (t < st) { --bi; st = 128 * bi - ((bi * (bi - 1)) >> 1); }
    while (t >= st + (NT - bi)) { st += NT - bi; ++bi; }
    const int bj = bi + (t - st);
    const int i0 = bi * 32, j0 = bj * 32;
    const bool diag = (bi == bj);

    // per-lane metadata (lanes 0..31 hold the 32 rows / cols)
    float sqi_l = 0.f, sqj_l = 0.f; int yi_l = 0, yj_l = 0;
    if (lane < 32) {
        sqi_l = sqg[i0 + lane]; yi_l = y[i0 + lane];
        sqj_l = sqg[j0 + lane]; yj_l = y[j0 + lane];
    }

    // K-loop: 2x2 fragments of 16x16x32, K = 4 x 32, direct from global
    const v8s* xg = (const v8s*)xb;                    // 16 v8s chunks per row
    const v8s* arow = xg + (i0 + lr) * 16 + q;
    const v8s* brow = xg + (j0 + lr) * 16 + q;
    v4f acc[2][2];
    #pragma unroll
    for (int mt = 0; mt < 2; ++mt)
        #pragma unroll
        for (int nt = 0; nt < 2; ++nt)
            acc[mt][nt] = (v4f){0.f, 0.f, 0.f, 0.f};
    #pragma unroll
    for (int kk = 0; kk < 4; ++kk) {
        v8s a0 = arow[kk * 4];
        v8s a1 = arow[256 + kk * 4];     // +16 rows
        v8s b0 = brow[kk * 4];
        v8s b1 = brow[256 + kk * 4];
        acc[0][0] = __builtin_amdgcn_mfma_f32_16x16x32_bf16(a0, b0, acc[0][0], 0, 0, 0);
        acc[0][1] = __builtin_amdgcn_mfma_f32_16x16x32_bf16(a0, b1, acc[0][1], 0, 0, 0);
        acc[1][0] = __builtin_amdgcn_mfma_f32_16x16x32_bf16(a1, b0, acc[1][0], 0, 0, 0);
        acc[1][1] = __builtin_amdgcn_mfma_f32_16x16x32_bf16(a1, b1, acc[1][1], 0, 0, 0);
    }

    // hoist per-element metadata via shfl (C/D: col = lane&15, row = q*4 + reg)
    float si[2][4]; int yir[2][4];
    #pragma unroll
    for (int mt = 0; mt < 2; ++mt)
        #pragma unroll
        for (int r = 0; r < 4; ++r) {
            int rl = mt * 16 + q * 4 + r;
            si[mt][r] = __shfl(sqi_l, rl);
            yir[mt][r] = __shfl(yi_l, rl);
        }
    float sj[2]; int yjc[2];
    #pragma unroll
    for (int nt = 0; nt < 2; ++nt) {
        int cl = nt * 16 + lr;
        sj[nt] = __shfl(sqj_l, cl);
        yjc[nt] = __shfl(yj_l, cl);
    }

    // epilogue: dist -> exp -> masked row & col partials
    float rn[2][4], rd[2][4];
    float cn[2] = {0.f, 0.f}, cd[2] = {0.f, 0.f};
    #pragma unroll
    for (int mt = 0; mt < 2; ++mt) {
        #pragma unroll
        for (int r = 0; r < 4; ++r) {
            int ig = i0 + mt * 16 + q * 4 + r;
            float n = 0.f, d = 0.f;
            #pragma unroll
            for (int nt = 0; nt < 2; ++nt) {
                float dist = fmaxf(si[mt][r] + sj[nt] - 2.f * acc[mt][nt][r], 0.f);
                float e = __builtin_amdgcn_exp2f(dist * -0.014426950408889634f); // exp(-dist/100)
                bool ok = (yir[mt][r] == yjc[nt]) && (ig != (j0 + nt * 16 + lr));
                float me = ok ? e : 0.f;
                d += e; n += me;
                cd[nt] += e; cn[nt] += me;
            }
            rn[mt][r] = n; rd[mt][r] = d;
        }
    }

    // row partials: reduce over 16 cols (lr bits), all q groups independent
    #pragma unroll
    for (int mt = 0; mt < 2; ++mt)
        #pragma unroll
        for (int r = 0; r < 4; ++r)
            #pragma unroll
            for (int off = 1; off < 16; off <<= 1) {
                rn[mt][r] += __shfl_xor(rn[mt][r], off);
                rd[mt][r] += __shfl_xor(rd[mt][r], off);
            }
    // col partials: reduce over rows = in-lane (mt,r) + q bits (16, 32)
    #pragma unroll
    for (int nt = 0; nt < 2; ++nt)
        #pragma unroll
        for (int off = 16; off < 64; off <<= 1) {
            cn[nt] += __shfl_xor(cn[nt], off);
            cd[nt] += __shfl_xor(cd[nt], off);
        }

    float2* Qrow = Q + (bi * NT + bj) * 32;
    if (lr == 0) {                       // lanes 0,16,32,48: 8 rows each
        #pragma unroll
        for (int mt = 0; mt < 2; ++mt)
            #pragma unroll
            for (int r = 0; r < 4; ++r)
                Qrow[mt * 16 + q * 4 + r] = make_float2(rn[mt][r], rd[mt][r]);
    }
    if (!diag && q == 0) {               // lanes 0..15: 2 cols each
        float2* Qcol = Q + (bj * NT + bi) * 32;
        #pragma unroll
        for (int nt = 0; nt < 2; ++nt)
            Qcol[nt * 16 + lr] = make_float2(cn[nt], cd[nt]);
    }
}

__global__ __launch_bounds__(256) void snn_final(const float2* __restrict__ Q,
        float* __restrict__ out) {
    __shared__ float wsum[4];
    int i = blockIdx.x * 256 + threadIdx.x;
    int bi = i >> 5, il = i & 31;
    float n = 0.f, d = 0.f;
    #pragma unroll 8
    for (int b = 0; b < NT; ++b) {
        float2 v = Q[(bi * NT + b) * 32 + il];
        n += v.x; d += v.y;
    }
    float l = -__logf(n / d);
    #pragma unroll
    for (int off = 32; off > 0; off >>= 1) l += __shfl_down(l, off);
    if ((threadIdx.x & 63) == 0) wsum[threadIdx.x >> 6] = l;
    __syncthreads();
    if (threadIdx.x == 0)
        atomicAdd(out, (wsum[0] + wsum[1] + wsum[2] + wsum[3]) * (1.0f / NB));
}

extern "C" void kernel_launch(void* const* d_in, const int* in_sizes, int n_in,
                              void* d_out, int out_size, void* d_ws, size_t ws_size,
                              hipStream_t stream) {
    const float* x = (const float*)d_in[0];
    const int*   y = (const int*)d_in[1];
    float* out = (float*)d_out;
    float* sq  = (float*)d_ws;
    unsigned short* xb = (unsigned short*)(sq + NB);
    float2* Q = (float2*)(xb + NB * 128);

    prep_kernel<<<NB / 8, 256, 0, stream>>>(x, sq, out, xb);
    snn_wave<<<NTILES / 4, 256, 0, stream>>>(xb, y, sq, Q);
    snn_final<<<NB / 256, 256, 0, stream>>>(Q, out);
}